// Round 6
// baseline (2032.518 us; speedup 1.0000x reference)
//
#include <hip/hip_runtime.h>
#include <hip/hip_bf16.h>
#include <math.h>

#define W_    320
#define H_    256
#define HW_   81920      // H_*W_
#define BHW_  327680     // 4*HW_
#define PRM_TOT 49786

// prm layout offsets (floats)
#define OW3  0
#define OW5  4608
#define OW7  18432
#define OCK  46080
#define OCT  47808
#define OG3  49617
#define OB3  49625
#define OG5  49633
#define OB5  49657
#define OG7  49681
#define OB7  49729
#define OCKB 49777
#define OCTB 49780
#define OSIG 49783

__device__ __forceinline__ float dload(const void* p, size_t i, int isbf) {
  return isbf ? __bfloat162float(((const __hip_bfloat16*)p)[i])
              : ((const float*)p)[i];
}

// ---------------------------------------------------------------------------
// Per-tensor dtype detector (proven consistent in R4/R5; kept for safety).
// ---------------------------------------------------------------------------
__global__ __launch_bounds__(512) void k_detect(
    const void* t0, const void* t1, const void* t2, const void* t3,
    const void* t4, const void* t5, const void* t6, const void* t7,
    const void* t8, const void* t9, const void* t10, const void* t11,
    const void* t12, const void* t13, const void* t14, const void* t15,
    const void* t16, const void* t17, int* __restrict__ flags)
{
  __shared__ int c_other, c_zeven, c_zodd, c_m;
  const void* ptrs[18] = {t0,t1,t2,t3,t4,t5,t6,t7,t8,t9,
                          t10,t11,t12,t13,t14,t15,t16,t17};
  const int ns[18] = {20971520, 327680, 4608, 8, 8, 13824, 24, 24,
                      27648, 48, 48, 1728, 3, 1809, 3, 1, 1, 1};
  const int tensor = blockIdx.x;
  const int n = ns[tensor];
  const unsigned short* u = (const unsigned short*)ptrs[tensor];
  if (threadIdx.x == 0) { c_other = 0; c_zeven = 0; c_zodd = 0; c_m = 0; }
  __syncthreads();
  {
    int k = threadIdx.x >> 1;
    long long pos = (long long)k * n / 256;
    int j = ((int)pos & ~1) + (threadIdx.x & 1);
    if (j < n) {
      unsigned short v = u[j];
      int e = (v >> 7) & 0xFF;
      atomicAdd(&c_m, 1);
      if (v != 0 && (e < 90 || e > 150)) atomicAdd(&c_other, 1);
      if (v == 0) {
        if (j & 1) atomicAdd(&c_zodd, 1); else atomicAdd(&c_zeven, 1);
      }
    }
  }
  __syncthreads();
  if (threadIdx.x == 0) {
    int isf32;
    if (n == 1) isf32 = (u[0] == 0);
    else        isf32 = (4 * c_other >= c_m) ||
                        (2 * (c_zeven - c_zodd) >= c_m);
    flags[tensor] = isf32 ? 0 : 1;
  }
}

// ---------------------------------------------------------------------------
// K0: convert params to f32 staging `prm` (per-tensor dtype).
// ---------------------------------------------------------------------------
__global__ __launch_bounds__(256) void k_cvt(
    const void* w3c, const void* w5c, const void* w7c, const void* ckw, const void* ctw,
    const void* g3, const void* b3, const void* g5, const void* b5,
    const void* g7, const void* b7, const void* ckb, const void* ctb,
    const void* s3, const void* s5, const void* s7,
    float* __restrict__ prm, const int* __restrict__ flags)
{
  int j = blockIdx.x * 256 + threadIdx.x;
  if (j >= PRM_TOT) return;
  const void* src; int off; int fid;
  if      (j < OW5)    { src = w3c; off = OW3;  fid = 2; }
  else if (j < OW7)    { src = w5c; off = OW5;  fid = 5; }
  else if (j < OCK)    { src = w7c; off = OW7;  fid = 8; }
  else if (j < OCT)    { src = ckw; off = OCK;  fid = 11; }
  else if (j < OG3)    { src = ctw; off = OCT;  fid = 13; }
  else if (j < OB3)    { src = g3;  off = OG3;  fid = 3; }
  else if (j < OG5)    { src = b3;  off = OB3;  fid = 4; }
  else if (j < OB5)    { src = g5;  off = OG5;  fid = 6; }
  else if (j < OG7)    { src = b5;  off = OB5;  fid = 7; }
  else if (j < OB7)    { src = g7;  off = OG7;  fid = 9; }
  else if (j < OCKB)   { src = b7;  off = OB7;  fid = 10; }
  else if (j < OCTB)   { src = ckb; off = OCKB; fid = 12; }
  else if (j < OSIG)   { src = ctb; off = OCTB; fid = 14; }
  else if (j < OSIG+1) { src = s3;  off = OSIG;   fid = 15; }
  else if (j < OSIG+2) { src = s5;  off = OSIG+1; fid = 16; }
  else                 { src = s7;  off = OSIG+2; fid = 17; }
  prm[j] = dload(src, j - off, flags[fid]);
}

// ---------------------------------------------------------------------------
// K1: direct 3x3 conv 64->83 + BN stats. One thread per output pixel.
// No LDS tiling — direct bounds-checked loads.
// ---------------------------------------------------------------------------
__global__ __launch_bounds__(256) void k_conv_direct(
    const void* __restrict__ fout, const float* __restrict__ prm,
    float* __restrict__ wbuf, float* __restrict__ stat,
    const int* __restrict__ flags)
{
  __shared__ float sred[160];
  const int tid = threadIdx.x;
  for (int i = tid; i < 160; i += 256) sred[i] = 0.f;
  __syncthreads();
  const int isbf = flags[0];
  const int p = blockIdx.x * 256 + tid;          // 1280*256 == BHW exactly
  const int b = p / HW_, q = p - b * HW_;
  const int y = q / W_, x = q - y * W_;

  float acc[83];
#pragma unroll
  for (int i = 0; i < 83; ++i) acc[i] = 0.f;

  for (int ic = 0; ic < 64; ++ic) {
    float t[9];
#pragma unroll
    for (int kh = 0; kh < 3; ++kh)
#pragma unroll
      for (int kw = 0; kw < 3; ++kw) {
        int gy = y + kh - 1, gx = x + kw - 1;
        float v = 0.f;
        if ((unsigned)gy < H_ && (unsigned)gx < W_)
          v = dload(fout, ((size_t)(b * 64 + ic)) * HW_ + (size_t)gy * W_ + gx, isbf);
        t[kh * 3 + kw] = v;
      }
    const float* w3 = prm + OW3 + ic * 9;        // OIHW: oc*576 + ic*9 + k
#pragma unroll
    for (int oc = 0; oc < 8; ++oc) {
      float a = acc[oc];
#pragma unroll
      for (int k = 0; k < 9; ++k) a = fmaf(t[k], w3[oc * 576 + k], a);
      acc[oc] = a;
    }
    const float* w5 = prm + OW5 + ic * 9;
#pragma unroll
    for (int oc = 0; oc < 24; ++oc) {
      float a = acc[8 + oc];
#pragma unroll
      for (int k = 0; k < 9; ++k) a = fmaf(t[k], w5[oc * 576 + k], a);
      acc[8 + oc] = a;
    }
    const float* w7 = prm + OW7 + ic * 9;
#pragma unroll
    for (int oc = 0; oc < 48; ++oc) {
      float a = acc[32 + oc];
#pragma unroll
      for (int k = 0; k < 9; ++k) a = fmaf(t[k], w7[oc * 576 + k], a);
      acc[32 + oc] = a;
    }
    const float* ck = prm + OCK + ic * 9;
#pragma unroll
    for (int oc = 0; oc < 3; ++oc) {
      float a = acc[80 + oc];
#pragma unroll
      for (int k = 0; k < 9; ++k) a = fmaf(t[k], ck[oc * 576 + k], a);
      acc[80 + oc] = a;
    }
  }

#pragma unroll
  for (int ch = 0; ch < 83; ++ch)
    wbuf[((size_t)b * 83 + ch) * HW_ + q] = acc[ch];

  // BN stats: butterfly wave-reduce, lane0 -> LDS atomics, then global.
  const int lane = tid & 63;
  for (int ch = 0; ch < 80; ++ch) {
    float s = acc[ch];
    float qq = s * s;
#pragma unroll
    for (int m = 1; m < 64; m <<= 1) {
      s += __shfl_xor(s, m, 64);
      qq += __shfl_xor(qq, m, 64);
    }
    if (lane == 0) { atomicAdd(&sred[ch], s); atomicAdd(&sred[80 + ch], qq); }
  }
  __syncthreads();
  if (tid < 160) atomicAdd(&stat[tid], sred[tid]);
}

// ---------------------------------------------------------------------------
// K1b: finalize BN mean / invstd
// ---------------------------------------------------------------------------
__global__ void k_bn_finalize(float* __restrict__ stat)
{
  int ch = threadIdx.x;
  if (ch < 80) {
    const float n = 1.f / (float)BHW_;
    float m = stat[ch] * n;
    float var = stat[80 + ch] * n - m * m;
    stat[160 + ch] = m;
    stat[240 + ch] = rsqrtf(var + 1e-5f);
  }
}

// ---------------------------------------------------------------------------
// K2: weight generation. Strict phases: load 83 -> compute kout[83] -> write.
// In-place over wbuf (per-thread own pixel column).
// ---------------------------------------------------------------------------
__global__ __launch_bounds__(256) void k_weights(
    float* __restrict__ wbuf, float* __restrict__ conf,
    const float* __restrict__ prm, const float* __restrict__ stat)
{
  const int p = blockIdx.x * 256 + threadIdx.x;
  const int b = p / HW_, q = p - b * HW_;
  float* base = wbuf + ((size_t)b * 83) * HW_ + q;

  float cv[83];
#pragma unroll
  for (int ch = 0; ch < 83; ++ch) cv[ch] = base[(size_t)ch * HW_];

  const float* mean = stat + 160;
  const float* istd = stat + 240;
#pragma unroll
  for (int ch = 0; ch < 8; ++ch)
    cv[ch] = fmaxf(0.f, (cv[ch] - mean[ch]) * istd[ch] * prm[OG3 + ch] + prm[OB3 + ch]);
#pragma unroll
  for (int ch = 0; ch < 24; ++ch)
    cv[8 + ch] = fmaxf(0.f, (cv[8 + ch] - mean[8 + ch]) * istd[8 + ch] * prm[OG5 + ch] + prm[OB5 + ch]);
#pragma unroll
  for (int ch = 0; ch < 48; ++ch)
    cv[32 + ch] = fmaxf(0.f, (cv[32 + ch] - mean[32 + ch]) * istd[32 + ch] * prm[OG7 + ch] + prm[OB7 + ch]);

  float kout[83];

  // ---- pk=3: cv[0..7] -> kout[0..8] ----
  {
    float s = 0.f;
#pragma unroll
    for (int i = 0; i < 8; ++i) s += cv[i];
    float inv = 1.f / (s + 1e-6f);
    float wn[8]; float sn = 0.f;
#pragma unroll
    for (int i = 0; i < 8; ++i) { wn[i] = cv[i] * inv; sn += wn[i]; }
    float kk[9];
#pragma unroll
    for (int j = 0; j < 4; ++j) kk[j] = wn[j];
    kk[4] = 1.f - sn;
#pragma unroll
    for (int j = 0; j < 4; ++j) kk[5 + j] = wn[4 + j];
    float sg = prm[OSIG + 0];
    float a = 0.5f / (sg * sg);
    float e1 = expf(-a);
    float g1[3] = {e1, 1.f, e1};
    float tot = 0.f;
#pragma unroll
    for (int j = 0; j < 9; ++j) { kk[j] *= g1[j / 3] * g1[j % 3]; tot += kk[j]; }
    float rr = 1.f / fmaxf(tot, 1e-7f);
#pragma unroll
    for (int j = 0; j < 9; ++j) kout[j] = kk[j] * rr;
  }
  // ---- pk=5: cv[8..31] -> kout[9..33] ----
  {
    float s = 0.f;
#pragma unroll
    for (int i = 0; i < 24; ++i) s += cv[8 + i];
    float inv = 1.f / (s + 1e-6f);
    float wn[24]; float sn = 0.f;
#pragma unroll
    for (int i = 0; i < 24; ++i) { wn[i] = cv[8 + i] * inv; sn += wn[i]; }
    float kk[25];
#pragma unroll
    for (int j = 0; j < 12; ++j) kk[j] = wn[j];
    kk[12] = 1.f - sn;
#pragma unroll
    for (int j = 0; j < 12; ++j) kk[13 + j] = wn[12 + j];
    float sg = prm[OSIG + 1];
    float a = 0.5f / (sg * sg);
    float ea = expf(-a), eb = expf(-0.25f * a);
    float g1[5] = {ea, eb, 1.f, eb, ea};
    float tot = 0.f;
#pragma unroll
    for (int j = 0; j < 25; ++j) { kk[j] *= g1[j / 5] * g1[j % 5]; tot += kk[j]; }
    float rr = 1.f / fmaxf(tot, 1e-7f);
#pragma unroll
    for (int j = 0; j < 25; ++j) kout[9 + j] = kk[j] * rr;
  }
  // ---- pk=7: cv[32..79] -> kout[34..82] ----
  {
    float s = 0.f;
#pragma unroll
    for (int i = 0; i < 48; ++i) s += cv[32 + i];
    float inv = 1.f / (s + 1e-6f);
    float wn[48]; float sn = 0.f;
#pragma unroll
    for (int i = 0; i < 48; ++i) { wn[i] = cv[32 + i] * inv; sn += wn[i]; }
    float kk[49];
#pragma unroll
    for (int j = 0; j < 24; ++j) kk[j] = wn[j];
    kk[24] = 1.f - sn;
#pragma unroll
    for (int j = 0; j < 24; ++j) kk[25 + j] = wn[24 + j];
    float sg = prm[OSIG + 2];
    float a = 0.5f / (sg * sg);
    float ea = expf(-a), eb = expf(-(4.f / 9.f) * a), ec = expf(-(1.f / 9.f) * a);
    float g1[7] = {ea, eb, ec, 1.f, ec, eb, ea};
    float tot = 0.f;
#pragma unroll
    for (int j = 0; j < 49; ++j) { kk[j] *= g1[j / 7] * g1[j % 7]; tot += kk[j]; }
    float rr = 1.f / fmaxf(tot, 1e-7f);
#pragma unroll
    for (int j = 0; j < 49; ++j) kout[34 + j] = kk[j] * rr;
  }

#pragma unroll
  for (int ch = 0; ch < 83; ++ch) base[(size_t)ch * HW_] = kout[ch];

  // ---- conf softmax over ck channels ----
  {
    float c0 = cv[80] + prm[OCKB + 0];
    float c1 = cv[81] + prm[OCKB + 1];
    float c2 = cv[82] + prm[OCKB + 2];
    float m = fmaxf(c0, fmaxf(c1, c2));
    float e0 = expf(c0 - m), e1 = expf(c1 - m), e2 = expf(c2 - m);
    float inv = 1.f / (e0 + e1 + e2);
    float* cf = conf + ((size_t)b * 3) * HW_ + q;
    cf[0] = e0 * inv;
    cf[(size_t)HW_] = e1 * inv;
    cf[(size_t)2 * HW_] = e2 * inv;
  }
}

// ---------------------------------------------------------------------------
// K3: direct propagation step, all three branches. One thread per pixel,
// bounds-checked direct loads (no LDS).
// ---------------------------------------------------------------------------
__global__ __launch_bounds__(256) void k_prop(
    const float* __restrict__ wbuf, const float* __restrict__ conf,
    const void* __restrict__ rawhn,
    const float* __restrict__ h3i, const float* __restrict__ h5i,
    const float* __restrict__ h7i,
    float* __restrict__ h3o, float* __restrict__ h5o, float* __restrict__ h7o,
    float* __restrict__ combo, int in_raw, const int* __restrict__ flags)
{
  const int isbf = flags[1];
  const int p = blockIdx.x * 256 + threadIdx.x;
  const int b = p / HW_, q = p - b * HW_;
  const int y = q / W_, x = q - y * W_;
  const size_t bo = (size_t)b * HW_;
  const float* wb = wbuf + ((size_t)b * 83) * HW_ + q;

  float a3 = 0.f, a5 = 0.f, a7 = 0.f;
#pragma unroll
  for (int j = 0; j < 9; ++j) {
    int gy = y + j / 3 - 1, gx = x + j % 3 - 1;
    float v = 0.f;
    if ((unsigned)gy < H_ && (unsigned)gx < W_) {
      size_t gi = bo + (size_t)gy * W_ + gx;
      v = in_raw ? dload(rawhn, gi, isbf) : h3i[gi];
    }
    a3 = fmaf(wb[(size_t)j * HW_], v, a3);
  }
#pragma unroll
  for (int j = 0; j < 25; ++j) {
    int gy = y + j / 5 - 2, gx = x + j % 5 - 2;
    float v = 0.f;
    if ((unsigned)gy < H_ && (unsigned)gx < W_) {
      size_t gi = bo + (size_t)gy * W_ + gx;
      v = in_raw ? dload(rawhn, gi, isbf) : h5i[gi];
    }
    a5 = fmaf(wb[(size_t)(9 + j) * HW_], v, a5);
  }
#pragma unroll
  for (int j = 0; j < 49; ++j) {
    int gy = y + j / 7 - 3, gx = x + j % 7 - 3;
    float v = 0.f;
    if ((unsigned)gy < H_ && (unsigned)gx < W_) {
      size_t gi = bo + (size_t)gy * W_ + gx;
      v = in_raw ? dload(rawhn, gi, isbf) : h7i[gi];
    }
    a7 = fmaf(wb[(size_t)(34 + j) * HW_], v, a7);
  }
  h3o[bo + q] = a3;
  h5o[bo + q] = a5;
  h7o[bo + q] = a7;
  if (combo) {
    const float* cf = conf + ((size_t)b * 3) * HW_ + q;
    combo[bo + q] = cf[0] * a3 + cf[(size_t)HW_] * a5 + cf[(size_t)2 * HW_] * a7;
  }
}

// ---------------------------------------------------------------------------
// K4: direct final conv (67ch -> 3) + softmax + dot. One thread per pixel.
// ---------------------------------------------------------------------------
__global__ __launch_bounds__(256) void k_final(
    const void* __restrict__ fout, const void* __restrict__ rawhn,
    const float* __restrict__ mid, const float* __restrict__ fin,
    const float* __restrict__ prm, float* __restrict__ out,
    const int* __restrict__ flags)
{
  const int isbf_f = flags[0];
  const int isbf_h = flags[1];
  const float* ctw = prm + OCT;
  const int p = blockIdx.x * 256 + threadIdx.x;
  const int b = p / HW_, q = p - b * HW_;
  const int y = q / W_, x = q - y * W_;
  const size_t bo = (size_t)b * HW_;

  float l0 = prm[OCTB + 0], l1 = prm[OCTB + 1], l2 = prm[OCTB + 2];

  for (int ic = 0; ic < 64; ++ic) {
#pragma unroll
    for (int j = 0; j < 9; ++j) {
      int gy = y + j / 3 - 1, gx = x + j % 3 - 1;
      float v = 0.f;
      if ((unsigned)gy < H_ && (unsigned)gx < W_)
        v = dload(fout, ((size_t)(b * 64 + ic)) * HW_ + (size_t)gy * W_ + gx, isbf_f);
      l0 = fmaf(v, ctw[(0 * 67 + ic) * 9 + j], l0);
      l1 = fmaf(v, ctw[(1 * 67 + ic) * 9 + j], l1);
      l2 = fmaf(v, ctw[(2 * 67 + ic) * 9 + j], l2);
    }
  }
#pragma unroll
  for (int c = 0; c < 3; ++c) {
    const int icg = 64 + c;
#pragma unroll
    for (int j = 0; j < 9; ++j) {
      int gy = y + j / 3 - 1, gx = x + j % 3 - 1;
      float v = 0.f;
      if ((unsigned)gy < H_ && (unsigned)gx < W_) {
        size_t gi = bo + (size_t)gy * W_ + gx;
        v = (c == 0) ? dload(rawhn, gi, isbf_h) : (c == 1) ? mid[gi] : fin[gi];
      }
      l0 = fmaf(v, ctw[(0 * 67 + icg) * 9 + j], l0);
      l1 = fmaf(v, ctw[(1 * 67 + icg) * 9 + j], l1);
      l2 = fmaf(v, ctw[(2 * 67 + icg) * 9 + j], l2);
    }
  }
  float m = fmaxf(l0, fmaxf(l1, l2));
  float e0 = expf(l0 - m), e1 = expf(l1 - m), e2 = expf(l2 - m);
  float inv = 1.f / (e0 + e1 + e2);
  float h0c = dload(rawhn, bo + q, isbf_h);
  float r = (e0 * h0c + e1 * mid[bo + q] + e2 * fin[bo + q]) * inv;
  out[bo + q] = r;
}

// ---------------------------------------------------------------------------
// Host launch
// ---------------------------------------------------------------------------
extern "C" void kernel_launch(void* const* d_in, const int* in_sizes, int n_in,
                              void* d_out, int out_size, void* d_ws, size_t ws_size,
                              hipStream_t stream)
{
  // Expected sizes in setup_inputs() dict order.
  static const int EXP[19] = {20971520, 327680, 327680, 4608, 8, 8, 13824, 24, 24,
                              27648, 48, 48, 1728, 3, 1809, 3, 1, 1, 1};
  const void* P[19];
  bool match = (n_in >= 19);
  for (int i = 0; i < 19 && match; ++i) if (in_sizes[i] != EXP[i]) match = false;
  if (match) {
    for (int i = 0; i < 19; ++i) P[i] = d_in[i];
  } else {
    bool used[64] = {false};
    for (int t = 0; t < 19; ++t) {
      P[t] = d_in[t < n_in ? t : 0];
      for (int i = 0; i < n_in && i < 64; ++i)
        if (!used[i] && in_sizes[i] == EXP[t]) { P[t] = d_in[i]; used[i] = true; break; }
    }
  }
  const void* fout = P[0];
  const void* hn   = P[1];
  float* out = (float*)d_out;

  // ws layout (floats), small buffers FIRST:
  // [0,32) flags(18 ints) | [32,352) stat | [352,50138) prm | big @50176
  float* ws    = (float*)d_ws;
  int*   flags = (int*)ws;
  float* stat  = ws + 32;
  float* prm   = ws + 352;
  float* big   = ws + 50176;
  float* wbuf  = big;                              // 83*BHW
  float* conf  = wbuf + (size_t)83 * BHW_;         // 3*BHW
  float* hnA   = conf + (size_t)3 * BHW_;          // 3*BHW
  float* hnB   = hnA + (size_t)3 * BHW_;           // 3*BHW
  float* midb  = hnB + (size_t)3 * BHW_;           // BHW
  float* finb  = midb + (size_t)BHW_;              // BHW

  (void)hipMemsetAsync(stat, 0, 160 * sizeof(float), stream);

  k_detect<<<18, 512, 0, stream>>>(
      P[0], P[1], P[3], P[4], P[5], P[6], P[7], P[8],
      P[9], P[10], P[11], P[12], P[13], P[14], P[15],
      P[16], P[17], P[18], flags);

  k_cvt<<<(PRM_TOT + 255) / 256, 256, 0, stream>>>(
      P[3], P[6], P[9], P[12], P[14],
      P[4], P[5], P[7], P[8], P[10], P[11],
      P[13], P[15], P[16], P[17], P[18], prm, flags);

  k_conv_direct<<<1280, 256, 0, stream>>>(fout, prm, wbuf, stat, flags);
  k_bn_finalize<<<1, 128, 0, stream>>>(stat);
  k_weights<<<1280, 256, 0, stream>>>(wbuf, conf, prm, stat);

  const float* i3 = nullptr;
  const float* i5 = nullptr;
  const float* i7 = nullptr;
  for (int it = 0; it < 6; ++it) {
    float* base = (it & 1) ? hnB : hnA;
    float* o3 = base;
    float* o5 = base + (size_t)BHW_;
    float* o7 = base + (size_t)2 * BHW_;
    float* combo = (it == 2) ? midb : (it == 5) ? finb : nullptr;
    k_prop<<<1280, 256, 0, stream>>>(
        wbuf, conf, hn, (it == 0) ? hnA : i3, (it == 0) ? hnA : i5,
        (it == 0) ? hnA : i7, o3, o5, o7, combo, (it == 0) ? 1 : 0, flags);
    i3 = o3; i5 = o5; i7 = o7;
  }

  k_final<<<1280, 256, 0, stream>>>(fout, hn, midb, finb, prm, out, flags);
}

// Round 7
// 2024.228 us; speedup vs baseline: 1.0041x; 1.0041x over previous
//
#include <hip/hip_runtime.h>
#include <hip/hip_bf16.h>
#include <math.h>

#define W_    320
#define H_    256
#define HW_   81920      // H_*W_
#define BHW_  327680     // 4*HW_
#define PRM_TOT 49786

// prm layout offsets (floats)
#define OW3  0
#define OW5  4608
#define OW7  18432
#define OCK  46080
#define OCT  47808
#define OG3  49617
#define OB3  49625
#define OG5  49633
#define OB5  49657
#define OG7  49681
#define OB7  49729
#define OCKB 49777
#define OCTB 49780
#define OSIG 49783

__device__ __forceinline__ float dload(const void* p, size_t i, int isbf) {
  return isbf ? __bfloat162float(((const __hip_bfloat16*)p)[i])
              : ((const float*)p)[i];
}

// ---------------------------------------------------------------------------
// Per-tensor dtype detector (kept for robustness; observed: all f32).
// ---------------------------------------------------------------------------
__global__ __launch_bounds__(512) void k_detect(
    const void* t0, const void* t1, const void* t2, const void* t3,
    const void* t4, const void* t5, const void* t6, const void* t7,
    const void* t8, const void* t9, const void* t10, const void* t11,
    const void* t12, const void* t13, const void* t14, const void* t15,
    const void* t16, const void* t17, int* __restrict__ flags)
{
  __shared__ int c_other, c_zeven, c_zodd, c_m;
  const void* ptrs[18] = {t0,t1,t2,t3,t4,t5,t6,t7,t8,t9,
                          t10,t11,t12,t13,t14,t15,t16,t17};
  const int ns[18] = {20971520, 327680, 4608, 8, 8, 13824, 24, 24,
                      27648, 48, 48, 1728, 3, 1809, 3, 1, 1, 1};
  const int tensor = blockIdx.x;
  const int n = ns[tensor];
  const unsigned short* u = (const unsigned short*)ptrs[tensor];
  if (threadIdx.x == 0) { c_other = 0; c_zeven = 0; c_zodd = 0; c_m = 0; }
  __syncthreads();
  {
    int k = threadIdx.x >> 1;
    long long pos = (long long)k * n / 256;
    int j = ((int)pos & ~1) + (threadIdx.x & 1);
    if (j < n) {
      unsigned short v = u[j];
      int e = (v >> 7) & 0xFF;
      atomicAdd(&c_m, 1);
      if (v != 0 && (e < 90 || e > 150)) atomicAdd(&c_other, 1);
      if (v == 0) {
        if (j & 1) atomicAdd(&c_zodd, 1); else atomicAdd(&c_zeven, 1);
      }
    }
  }
  __syncthreads();
  if (threadIdx.x == 0) {
    int isf32;
    if (n == 1) isf32 = (u[0] == 0);
    else        isf32 = (4 * c_other >= c_m) ||
                        (2 * (c_zeven - c_zodd) >= c_m);
    flags[tensor] = isf32 ? 0 : 1;
  }
}

// ---------------------------------------------------------------------------
// K0: convert params to f32 staging `prm` (per-tensor dtype).
// ---------------------------------------------------------------------------
__global__ __launch_bounds__(256) void k_cvt(
    const void* w3c, const void* w5c, const void* w7c, const void* ckw, const void* ctw,
    const void* g3, const void* b3, const void* g5, const void* b5,
    const void* g7, const void* b7, const void* ckb, const void* ctb,
    const void* s3, const void* s5, const void* s7,
    float* __restrict__ prm, const int* __restrict__ flags)
{
  int j = blockIdx.x * 256 + threadIdx.x;
  if (j >= PRM_TOT) return;
  const void* src; int off; int fid;
  if      (j < OW5)    { src = w3c; off = OW3;  fid = 2; }
  else if (j < OW7)    { src = w5c; off = OW5;  fid = 5; }
  else if (j < OCK)    { src = w7c; off = OW7;  fid = 8; }
  else if (j < OCT)    { src = ckw; off = OCK;  fid = 11; }
  else if (j < OG3)    { src = ctw; off = OCT;  fid = 13; }
  else if (j < OB3)    { src = g3;  off = OG3;  fid = 3; }
  else if (j < OG5)    { src = b3;  off = OB3;  fid = 4; }
  else if (j < OB5)    { src = g5;  off = OG5;  fid = 6; }
  else if (j < OG7)    { src = b5;  off = OB5;  fid = 7; }
  else if (j < OB7)    { src = g7;  off = OG7;  fid = 9; }
  else if (j < OCKB)   { src = b7;  off = OB7;  fid = 10; }
  else if (j < OCTB)   { src = ckb; off = OCKB; fid = 12; }
  else if (j < OSIG)   { src = ctb; off = OCTB; fid = 14; }
  else if (j < OSIG+1) { src = s3;  off = OSIG;   fid = 15; }
  else if (j < OSIG+2) { src = s5;  off = OSIG+1; fid = 16; }
  else                 { src = s7;  off = OSIG+2; fid = 17; }
  prm[j] = dload(src, j - off, flags[fid]);
}

// ---------------------------------------------------------------------------
// K1: direct 3x3 conv 64->83 + BN stats. One thread per output pixel.
// __launch_bounds__(256,2): min 2 waves/EU -> 256-VGPR cap so acc[83]
// stays in registers (R6 spilled at VGPR=64 -> 7 GB scratch traffic).
// ---------------------------------------------------------------------------
__global__ __launch_bounds__(256, 2) void k_conv_direct(
    const void* __restrict__ fout, const float* __restrict__ prm,
    float* __restrict__ wbuf, float* __restrict__ stat,
    const int* __restrict__ flags)
{
  __shared__ float sred[160];
  const int tid = threadIdx.x;
  for (int i = tid; i < 160; i += 256) sred[i] = 0.f;
  __syncthreads();
  const int isbf = flags[0];
  const int p = blockIdx.x * 256 + tid;          // 1280*256 == BHW exactly
  const int b = p / HW_, q = p - b * HW_;
  const int y = q / W_, x = q - y * W_;

  // Hoist tap offsets and validity out of the ic loop.
  size_t toff[9]; bool tok[9];
#pragma unroll
  for (int j = 0; j < 9; ++j) {
    int gy = y + j / 3 - 1, gx = x + j % 3 - 1;
    tok[j] = (unsigned)gy < H_ && (unsigned)gx < W_;
    toff[j] = (size_t)(b * 64) * HW_ + (size_t)gy * W_ + gx;
  }

  float acc[83];
#pragma unroll
  for (int i = 0; i < 83; ++i) acc[i] = 0.f;

  for (int ic = 0; ic < 64; ++ic) {
    float t[9];
#pragma unroll
    for (int j = 0; j < 9; ++j)
      t[j] = tok[j] ? dload(fout, toff[j] + (size_t)ic * HW_, isbf) : 0.f;
    const float* w3 = prm + OW3 + ic * 9;        // OIHW: oc*576 + ic*9 + k
#pragma unroll
    for (int oc = 0; oc < 8; ++oc) {
      float a = acc[oc];
#pragma unroll
      for (int k = 0; k < 9; ++k) a = fmaf(t[k], w3[oc * 576 + k], a);
      acc[oc] = a;
    }
    const float* w5 = prm + OW5 + ic * 9;
#pragma unroll
    for (int oc = 0; oc < 24; ++oc) {
      float a = acc[8 + oc];
#pragma unroll
      for (int k = 0; k < 9; ++k) a = fmaf(t[k], w5[oc * 576 + k], a);
      acc[8 + oc] = a;
    }
    const float* w7 = prm + OW7 + ic * 9;
#pragma unroll
    for (int oc = 0; oc < 48; ++oc) {
      float a = acc[32 + oc];
#pragma unroll
      for (int k = 0; k < 9; ++k) a = fmaf(t[k], w7[oc * 576 + k], a);
      acc[32 + oc] = a;
    }
    const float* ck = prm + OCK + ic * 9;
#pragma unroll
    for (int oc = 0; oc < 3; ++oc) {
      float a = acc[80 + oc];
#pragma unroll
      for (int k = 0; k < 9; ++k) a = fmaf(t[k], ck[oc * 576 + k], a);
      acc[80 + oc] = a;
    }
  }

#pragma unroll
  for (int ch = 0; ch < 83; ++ch)
    wbuf[((size_t)b * 83 + ch) * HW_ + q] = acc[ch];

  // BN stats: butterfly wave-reduce, lane0 -> LDS atomics, then global.
  const int lane = tid & 63;
  for (int ch = 0; ch < 80; ++ch) {
    float s = acc[ch];
    float qq = s * s;
#pragma unroll
    for (int m = 1; m < 64; m <<= 1) {
      s += __shfl_xor(s, m, 64);
      qq += __shfl_xor(qq, m, 64);
    }
    if (lane == 0) { atomicAdd(&sred[ch], s); atomicAdd(&sred[80 + ch], qq); }
  }
  __syncthreads();
  if (tid < 160) atomicAdd(&stat[tid], sred[tid]);
}

// ---------------------------------------------------------------------------
// K1b: finalize BN mean / invstd
// ---------------------------------------------------------------------------
__global__ void k_bn_finalize(float* __restrict__ stat)
{
  int ch = threadIdx.x;
  if (ch < 80) {
    const float n = 1.f / (float)BHW_;
    float m = stat[ch] * n;
    float var = stat[80 + ch] * n - m * m;
    stat[160 + ch] = m;
    stat[240 + ch] = rsqrtf(var + 1e-5f);
  }
}

// ---------------------------------------------------------------------------
// K2: weight generation. Strict phases: load 83 -> compute kout[83] -> write.
// ---------------------------------------------------------------------------
__global__ __launch_bounds__(256, 2) void k_weights(
    float* __restrict__ wbuf, float* __restrict__ conf,
    const float* __restrict__ prm, const float* __restrict__ stat)
{
  const int p = blockIdx.x * 256 + threadIdx.x;
  const int b = p / HW_, q = p - b * HW_;
  float* base = wbuf + ((size_t)b * 83) * HW_ + q;

  float cv[83];
#pragma unroll
  for (int ch = 0; ch < 83; ++ch) cv[ch] = base[(size_t)ch * HW_];

  const float* mean = stat + 160;
  const float* istd = stat + 240;
#pragma unroll
  for (int ch = 0; ch < 8; ++ch)
    cv[ch] = fmaxf(0.f, (cv[ch] - mean[ch]) * istd[ch] * prm[OG3 + ch] + prm[OB3 + ch]);
#pragma unroll
  for (int ch = 0; ch < 24; ++ch)
    cv[8 + ch] = fmaxf(0.f, (cv[8 + ch] - mean[8 + ch]) * istd[8 + ch] * prm[OG5 + ch] + prm[OB5 + ch]);
#pragma unroll
  for (int ch = 0; ch < 48; ++ch)
    cv[32 + ch] = fmaxf(0.f, (cv[32 + ch] - mean[32 + ch]) * istd[32 + ch] * prm[OG7 + ch] + prm[OB7 + ch]);

  float kout[83];

  // ---- pk=3: cv[0..7] -> kout[0..8] ----
  {
    float s = 0.f;
#pragma unroll
    for (int i = 0; i < 8; ++i) s += cv[i];
    float inv = 1.f / (s + 1e-6f);
    float wn[8]; float sn = 0.f;
#pragma unroll
    for (int i = 0; i < 8; ++i) { wn[i] = cv[i] * inv; sn += wn[i]; }
    float kk[9];
#pragma unroll
    for (int j = 0; j < 4; ++j) kk[j] = wn[j];
    kk[4] = 1.f - sn;
#pragma unroll
    for (int j = 0; j < 4; ++j) kk[5 + j] = wn[4 + j];
    float sg = prm[OSIG + 0];
    float a = 0.5f / (sg * sg);
    float e1 = expf(-a);
    float g1[3] = {e1, 1.f, e1};
    float tot = 0.f;
#pragma unroll
    for (int j = 0; j < 9; ++j) { kk[j] *= g1[j / 3] * g1[j % 3]; tot += kk[j]; }
    float rr = 1.f / fmaxf(tot, 1e-7f);
#pragma unroll
    for (int j = 0; j < 9; ++j) kout[j] = kk[j] * rr;
  }
  // ---- pk=5: cv[8..31] -> kout[9..33] ----
  {
    float s = 0.f;
#pragma unroll
    for (int i = 0; i < 24; ++i) s += cv[8 + i];
    float inv = 1.f / (s + 1e-6f);
    float wn[24]; float sn = 0.f;
#pragma unroll
    for (int i = 0; i < 24; ++i) { wn[i] = cv[8 + i] * inv; sn += wn[i]; }
    float kk[25];
#pragma unroll
    for (int j = 0; j < 12; ++j) kk[j] = wn[j];
    kk[12] = 1.f - sn;
#pragma unroll
    for (int j = 0; j < 12; ++j) kk[13 + j] = wn[12 + j];
    float sg = prm[OSIG + 1];
    float a = 0.5f / (sg * sg);
    float ea = expf(-a), eb = expf(-0.25f * a);
    float g1[5] = {ea, eb, 1.f, eb, ea};
    float tot = 0.f;
#pragma unroll
    for (int j = 0; j < 25; ++j) { kk[j] *= g1[j / 5] * g1[j % 5]; tot += kk[j]; }
    float rr = 1.f / fmaxf(tot, 1e-7f);
#pragma unroll
    for (int j = 0; j < 25; ++j) kout[9 + j] = kk[j] * rr;
  }
  // ---- pk=7: cv[32..79] -> kout[34..82] ----
  {
    float s = 0.f;
#pragma unroll
    for (int i = 0; i < 48; ++i) s += cv[32 + i];
    float inv = 1.f / (s + 1e-6f);
    float wn[48]; float sn = 0.f;
#pragma unroll
    for (int i = 0; i < 48; ++i) { wn[i] = cv[32 + i] * inv; sn += wn[i]; }
    float kk[49];
#pragma unroll
    for (int j = 0; j < 24; ++j) kk[j] = wn[j];
    kk[24] = 1.f - sn;
#pragma unroll
    for (int j = 0; j < 24; ++j) kk[25 + j] = wn[24 + j];
    float sg = prm[OSIG + 2];
    float a = 0.5f / (sg * sg);
    float ea = expf(-a), eb = expf(-(4.f / 9.f) * a), ec = expf(-(1.f / 9.f) * a);
    float g1[7] = {ea, eb, ec, 1.f, ec, eb, ea};
    float tot = 0.f;
#pragma unroll
    for (int j = 0; j < 49; ++j) { kk[j] *= g1[j / 7] * g1[j % 7]; tot += kk[j]; }
    float rr = 1.f / fmaxf(tot, 1e-7f);
#pragma unroll
    for (int j = 0; j < 49; ++j) kout[34 + j] = kk[j] * rr;
  }

#pragma unroll
  for (int ch = 0; ch < 83; ++ch) base[(size_t)ch * HW_] = kout[ch];

  // ---- conf softmax over ck channels ----
  {
    float c0 = cv[80] + prm[OCKB + 0];
    float c1 = cv[81] + prm[OCKB + 1];
    float c2 = cv[82] + prm[OCKB + 2];
    float m = fmaxf(c0, fmaxf(c1, c2));
    float e0 = expf(c0 - m), e1 = expf(c1 - m), e2 = expf(c2 - m);
    float inv = 1.f / (e0 + e1 + e2);
    float* cf = conf + ((size_t)b * 3) * HW_ + q;
    cf[0] = e0 * inv;
    cf[(size_t)HW_] = e1 * inv;
    cf[(size_t)2 * HW_] = e2 * inv;
  }
}

// ---------------------------------------------------------------------------
// K3: direct propagation step, all three branches. One thread per pixel.
// ---------------------------------------------------------------------------
__global__ __launch_bounds__(256, 2) void k_prop(
    const float* __restrict__ wbuf, const float* __restrict__ conf,
    const void* __restrict__ rawhn,
    const float* __restrict__ h3i, const float* __restrict__ h5i,
    const float* __restrict__ h7i,
    float* __restrict__ h3o, float* __restrict__ h5o, float* __restrict__ h7o,
    float* __restrict__ combo, int in_raw, const int* __restrict__ flags)
{
  const int isbf = flags[1];
  const int p = blockIdx.x * 256 + threadIdx.x;
  const int b = p / HW_, q = p - b * HW_;
  const int y = q / W_, x = q - y * W_;
  const size_t bo = (size_t)b * HW_;
  const float* wb = wbuf + ((size_t)b * 83) * HW_ + q;

  float a3 = 0.f, a5 = 0.f, a7 = 0.f;
#pragma unroll
  for (int j = 0; j < 9; ++j) {
    int gy = y + j / 3 - 1, gx = x + j % 3 - 1;
    float v = 0.f;
    if ((unsigned)gy < H_ && (unsigned)gx < W_) {
      size_t gi = bo + (size_t)gy * W_ + gx;
      v = in_raw ? dload(rawhn, gi, isbf) : h3i[gi];
    }
    a3 = fmaf(wb[(size_t)j * HW_], v, a3);
  }
#pragma unroll
  for (int j = 0; j < 25; ++j) {
    int gy = y + j / 5 - 2, gx = x + j % 5 - 2;
    float v = 0.f;
    if ((unsigned)gy < H_ && (unsigned)gx < W_) {
      size_t gi = bo + (size_t)gy * W_ + gx;
      v = in_raw ? dload(rawhn, gi, isbf) : h5i[gi];
    }
    a5 = fmaf(wb[(size_t)(9 + j) * HW_], v, a5);
  }
#pragma unroll
  for (int j = 0; j < 49; ++j) {
    int gy = y + j / 7 - 3, gx = x + j % 7 - 3;
    float v = 0.f;
    if ((unsigned)gy < H_ && (unsigned)gx < W_) {
      size_t gi = bo + (size_t)gy * W_ + gx;
      v = in_raw ? dload(rawhn, gi, isbf) : h7i[gi];
    }
    a7 = fmaf(wb[(size_t)(34 + j) * HW_], v, a7);
  }
  h3o[bo + q] = a3;
  h5o[bo + q] = a5;
  h7o[bo + q] = a7;
  if (combo) {
    const float* cf = conf + ((size_t)b * 3) * HW_ + q;
    combo[bo + q] = cf[0] * a3 + cf[(size_t)HW_] * a5 + cf[(size_t)2 * HW_] * a7;
  }
}

// ---------------------------------------------------------------------------
// K4: direct final conv (67ch -> 3) + softmax + dot. One thread per pixel.
// ---------------------------------------------------------------------------
__global__ __launch_bounds__(256, 2) void k_final(
    const void* __restrict__ fout, const void* __restrict__ rawhn,
    const float* __restrict__ mid, const float* __restrict__ fin,
    const float* __restrict__ prm, float* __restrict__ out,
    const int* __restrict__ flags)
{
  const int isbf_f = flags[0];
  const int isbf_h = flags[1];
  const float* ctw = prm + OCT;
  const int p = blockIdx.x * 256 + threadIdx.x;
  const int b = p / HW_, q = p - b * HW_;
  const int y = q / W_, x = q - y * W_;
  const size_t bo = (size_t)b * HW_;

  size_t toff[9]; bool tok[9];
#pragma unroll
  for (int j = 0; j < 9; ++j) {
    int gy = y + j / 3 - 1, gx = x + j % 3 - 1;
    tok[j] = (unsigned)gy < H_ && (unsigned)gx < W_;
    toff[j] = (size_t)(b * 64) * HW_ + (size_t)gy * W_ + gx;
  }

  float l0 = prm[OCTB + 0], l1 = prm[OCTB + 1], l2 = prm[OCTB + 2];

  for (int ic = 0; ic < 64; ++ic) {
#pragma unroll
    for (int j = 0; j < 9; ++j) {
      float v = tok[j] ? dload(fout, toff[j] + (size_t)ic * HW_, isbf_f) : 0.f;
      l0 = fmaf(v, ctw[(0 * 67 + ic) * 9 + j], l0);
      l1 = fmaf(v, ctw[(1 * 67 + ic) * 9 + j], l1);
      l2 = fmaf(v, ctw[(2 * 67 + ic) * 9 + j], l2);
    }
  }
#pragma unroll
  for (int c = 0; c < 3; ++c) {
    const int icg = 64 + c;
#pragma unroll
    for (int j = 0; j < 9; ++j) {
      int gy = y + j / 3 - 1, gx = x + j % 3 - 1;
      float v = 0.f;
      if ((unsigned)gy < H_ && (unsigned)gx < W_) {
        size_t gi = bo + (size_t)gy * W_ + gx;
        v = (c == 0) ? dload(rawhn, gi, isbf_h) : (c == 1) ? mid[gi] : fin[gi];
      }
      l0 = fmaf(v, ctw[(0 * 67 + icg) * 9 + j], l0);
      l1 = fmaf(v, ctw[(1 * 67 + icg) * 9 + j], l1);
      l2 = fmaf(v, ctw[(2 * 67 + icg) * 9 + j], l2);
    }
  }
  float m = fmaxf(l0, fmaxf(l1, l2));
  float e0 = expf(l0 - m), e1 = expf(l1 - m), e2 = expf(l2 - m);
  float inv = 1.f / (e0 + e1 + e2);
  float h0c = dload(rawhn, bo + q, isbf_h);
  float r = (e0 * h0c + e1 * mid[bo + q] + e2 * fin[bo + q]) * inv;
  out[bo + q] = r;
}

// ---------------------------------------------------------------------------
// Host launch
// ---------------------------------------------------------------------------
extern "C" void kernel_launch(void* const* d_in, const int* in_sizes, int n_in,
                              void* d_out, int out_size, void* d_ws, size_t ws_size,
                              hipStream_t stream)
{
  static const int EXP[19] = {20971520, 327680, 327680, 4608, 8, 8, 13824, 24, 24,
                              27648, 48, 48, 1728, 3, 1809, 3, 1, 1, 1};
  const void* P[19];
  bool match = (n_in >= 19);
  for (int i = 0; i < 19 && match; ++i) if (in_sizes[i] != EXP[i]) match = false;
  if (match) {
    for (int i = 0; i < 19; ++i) P[i] = d_in[i];
  } else {
    bool used[64] = {false};
    for (int t = 0; t < 19; ++t) {
      P[t] = d_in[t < n_in ? t : 0];
      for (int i = 0; i < n_in && i < 64; ++i)
        if (!used[i] && in_sizes[i] == EXP[t]) { P[t] = d_in[i]; used[i] = true; break; }
    }
  }
  const void* fout = P[0];
  const void* hn   = P[1];
  float* out = (float*)d_out;

  // ws layout (floats), small buffers FIRST:
  // [0,32) flags(18 ints) | [32,352) stat | [352,50138) prm | big @50176
  float* ws    = (float*)d_ws;
  int*   flags = (int*)ws;
  float* stat  = ws + 32;
  float* prm   = ws + 352;
  float* big   = ws + 50176;
  float* wbuf  = big;                              // 83*BHW
  float* conf  = wbuf + (size_t)83 * BHW_;         // 3*BHW
  float* hnA   = conf + (size_t)3 * BHW_;          // 3*BHW
  float* hnB   = hnA + (size_t)3 * BHW_;           // 3*BHW
  float* midb  = hnB + (size_t)3 * BHW_;           // BHW
  float* finb  = midb + (size_t)BHW_;              // BHW

  (void)hipMemsetAsync(stat, 0, 160 * sizeof(float), stream);

  k_detect<<<18, 512, 0, stream>>>(
      P[0], P[1], P[3], P[4], P[5], P[6], P[7], P[8],
      P[9], P[10], P[11], P[12], P[13], P[14], P[15],
      P[16], P[17], P[18], flags);

  k_cvt<<<(PRM_TOT + 255) / 256, 256, 0, stream>>>(
      P[3], P[6], P[9], P[12], P[14],
      P[4], P[5], P[7], P[8], P[10], P[11],
      P[13], P[15], P[16], P[17], P[18], prm, flags);

  k_conv_direct<<<1280, 256, 0, stream>>>(fout, prm, wbuf, stat, flags);
  k_bn_finalize<<<1, 128, 0, stream>>>(stat);
  k_weights<<<1280, 256, 0, stream>>>(wbuf, conf, prm, stat);

  const float* i3 = nullptr;
  const float* i5 = nullptr;
  const float* i7 = nullptr;
  for (int it = 0; it < 6; ++it) {
    float* base = (it & 1) ? hnB : hnA;
    float* o3 = base;
    float* o5 = base + (size_t)BHW_;
    float* o7 = base + (size_t)2 * BHW_;
    float* combo = (it == 2) ? midb : (it == 5) ? finb : nullptr;
    k_prop<<<1280, 256, 0, stream>>>(
        wbuf, conf, hn, (it == 0) ? hnA : i3, (it == 0) ? hnA : i5,
        (it == 0) ? hnA : i7, o3, o5, o7, combo, (it == 0) ? 1 : 0, flags);
    i3 = o3; i5 = o5; i7 = o7;
  }

  k_final<<<1280, 256, 0, stream>>>(fout, hn, midb, finb, prm, out, flags);
}

// Round 8
// 1349.101 us; speedup vs baseline: 1.5066x; 1.5004x over previous
//
#include <hip/hip_runtime.h>
#include <hip/hip_bf16.h>
#include <math.h>

#define W_    320
#define H_    256
#define HW_   81920      // H_*W_
#define BHW_  327680     // 4*HW_
#define PRM_TOT 49786

// prm layout offsets (floats)
#define OW3  0
#define OW5  4608
#define OW7  18432
#define OCK  46080
#define OCT  47808
#define OG3  49617
#define OB3  49625
#define OG5  49633
#define OB5  49657
#define OG7  49681
#define OB7  49729
#define OCKB 49777
#define OCTB 49780
#define OSIG 49783

__device__ __forceinline__ float dload(const void* p, size_t i, int isbf) {
  return isbf ? __bfloat162float(((const __hip_bfloat16*)p)[i])
              : ((const float*)p)[i];
}

// ---------------------------------------------------------------------------
// Per-tensor dtype detector (kept for robustness; observed: all f32).
// ---------------------------------------------------------------------------
__global__ __launch_bounds__(512) void k_detect(
    const void* t0, const void* t1, const void* t2, const void* t3,
    const void* t4, const void* t5, const void* t6, const void* t7,
    const void* t8, const void* t9, const void* t10, const void* t11,
    const void* t12, const void* t13, const void* t14, const void* t15,
    const void* t16, const void* t17, int* __restrict__ flags)
{
  __shared__ int c_other, c_zeven, c_zodd, c_m;
  const void* ptrs[18] = {t0,t1,t2,t3,t4,t5,t6,t7,t8,t9,
                          t10,t11,t12,t13,t14,t15,t16,t17};
  const int ns[18] = {20971520, 327680, 4608, 8, 8, 13824, 24, 24,
                      27648, 48, 48, 1728, 3, 1809, 3, 1, 1, 1};
  const int tensor = blockIdx.x;
  const int n = ns[tensor];
  const unsigned short* u = (const unsigned short*)ptrs[tensor];
  if (threadIdx.x == 0) { c_other = 0; c_zeven = 0; c_zodd = 0; c_m = 0; }
  __syncthreads();
  {
    int k = threadIdx.x >> 1;
    long long pos = (long long)k * n / 256;
    int j = ((int)pos & ~1) + (threadIdx.x & 1);
    if (j < n) {
      unsigned short v = u[j];
      int e = (v >> 7) & 0xFF;
      atomicAdd(&c_m, 1);
      if (v != 0 && (e < 90 || e > 150)) atomicAdd(&c_other, 1);
      if (v == 0) {
        if (j & 1) atomicAdd(&c_zodd, 1); else atomicAdd(&c_zeven, 1);
      }
    }
  }
  __syncthreads();
  if (threadIdx.x == 0) {
    int isf32;
    if (n == 1) isf32 = (u[0] == 0);
    else        isf32 = (4 * c_other >= c_m) ||
                        (2 * (c_zeven - c_zodd) >= c_m);
    flags[tensor] = isf32 ? 0 : 1;
  }
}

// ---------------------------------------------------------------------------
// K0: convert params to f32 staging `prm` (per-tensor dtype).
// ---------------------------------------------------------------------------
__global__ __launch_bounds__(256) void k_cvt(
    const void* w3c, const void* w5c, const void* w7c, const void* ckw, const void* ctw,
    const void* g3, const void* b3, const void* g5, const void* b5,
    const void* g7, const void* b7, const void* ckb, const void* ctb,
    const void* s3, const void* s5, const void* s7,
    float* __restrict__ prm, const int* __restrict__ flags)
{
  int j = blockIdx.x * 256 + threadIdx.x;
  if (j >= PRM_TOT) return;
  const void* src; int off; int fid;
  if      (j < OW5)    { src = w3c; off = OW3;  fid = 2; }
  else if (j < OW7)    { src = w5c; off = OW5;  fid = 5; }
  else if (j < OCK)    { src = w7c; off = OW7;  fid = 8; }
  else if (j < OCT)    { src = ckw; off = OCK;  fid = 11; }
  else if (j < OG3)    { src = ctw; off = OCT;  fid = 13; }
  else if (j < OB3)    { src = g3;  off = OG3;  fid = 3; }
  else if (j < OG5)    { src = b3;  off = OB3;  fid = 4; }
  else if (j < OB5)    { src = g5;  off = OG5;  fid = 6; }
  else if (j < OG7)    { src = b5;  off = OB5;  fid = 7; }
  else if (j < OB7)    { src = g7;  off = OG7;  fid = 9; }
  else if (j < OCKB)   { src = b7;  off = OB7;  fid = 10; }
  else if (j < OCTB)   { src = ckb; off = OCKB; fid = 12; }
  else if (j < OSIG)   { src = ctb; off = OCTB; fid = 14; }
  else if (j < OSIG+1) { src = s3;  off = OSIG;   fid = 15; }
  else if (j < OSIG+2) { src = s5;  off = OSIG+1; fid = 16; }
  else                 { src = s7;  off = OSIG+2; fid = 17; }
  prm[j] = dload(src, j - off, flags[fid]);
}

// ---------------------------------------------------------------------------
// K1: direct 3x3 conv 64->83. One thread per output pixel. NO dynamic
// indexing into local arrays anywhere (R7 lesson: the non-unrolled BN-stats
// loop indexed acc[ch] dynamically -> whole acc[] lived in scratch -> 7 GB
// of spill traffic). BN stats moved to k_stats.
// ---------------------------------------------------------------------------
__global__ __launch_bounds__(256, 2) void k_conv_direct(
    const void* __restrict__ fout, const float* __restrict__ prm,
    float* __restrict__ wbuf, const int* __restrict__ flags)
{
  const int isbf = flags[0];
  const int tid = threadIdx.x;
  const int p = blockIdx.x * 256 + tid;          // 1280*256 == BHW exactly
  const int b = p / HW_, q = p - b * HW_;
  const int y = q / W_, x = q - y * W_;

  size_t toff[9]; bool tok[9];
#pragma unroll
  for (int j = 0; j < 9; ++j) {
    int gy = y + j / 3 - 1, gx = x + j % 3 - 1;
    tok[j] = (unsigned)gy < H_ && (unsigned)gx < W_;
    toff[j] = (size_t)(b * 64) * HW_ + (size_t)gy * W_ + gx;
  }

  float acc[83];
#pragma unroll
  for (int i = 0; i < 83; ++i) acc[i] = 0.f;

  for (int ic = 0; ic < 64; ++ic) {
    float t[9];
#pragma unroll
    for (int j = 0; j < 9; ++j)
      t[j] = tok[j] ? dload(fout, toff[j] + (size_t)ic * HW_, isbf) : 0.f;
    const float* w3 = prm + OW3 + ic * 9;        // OIHW: oc*576 + ic*9 + k
#pragma unroll
    for (int oc = 0; oc < 8; ++oc) {
      float a = acc[oc];
#pragma unroll
      for (int k = 0; k < 9; ++k) a = fmaf(t[k], w3[oc * 576 + k], a);
      acc[oc] = a;
    }
    const float* w5 = prm + OW5 + ic * 9;
#pragma unroll
    for (int oc = 0; oc < 24; ++oc) {
      float a = acc[8 + oc];
#pragma unroll
      for (int k = 0; k < 9; ++k) a = fmaf(t[k], w5[oc * 576 + k], a);
      acc[8 + oc] = a;
    }
    const float* w7 = prm + OW7 + ic * 9;
#pragma unroll
    for (int oc = 0; oc < 48; ++oc) {
      float a = acc[32 + oc];
#pragma unroll
      for (int k = 0; k < 9; ++k) a = fmaf(t[k], w7[oc * 576 + k], a);
      acc[32 + oc] = a;
    }
    const float* ck = prm + OCK + ic * 9;
#pragma unroll
    for (int oc = 0; oc < 3; ++oc) {
      float a = acc[80 + oc];
#pragma unroll
      for (int k = 0; k < 9; ++k) a = fmaf(t[k], ck[oc * 576 + k], a);
      acc[80 + oc] = a;
    }
  }

#pragma unroll
  for (int ch = 0; ch < 83; ++ch)
    wbuf[((size_t)b * 83 + ch) * HW_ + q] = acc[ch];
}

// ---------------------------------------------------------------------------
// K1s: BN statistics over wbuf channels 0..79. grid=(32,80); channel per
// blockIdx.y; grid-stride over BHW. 109 MB extra read (~25 us) — cheap,
// and keeps k_conv free of dynamic-index scratch.
// ---------------------------------------------------------------------------
__global__ __launch_bounds__(256) void k_stats(
    const float* __restrict__ wbuf, float* __restrict__ stat)
{
  const int ch = blockIdx.y;
  float s = 0.f, qq = 0.f;
  for (int idx = blockIdx.x * 256 + threadIdx.x; idx < BHW_;
       idx += gridDim.x * 256) {
    int b = idx / HW_, r = idx - b * HW_;
    float v = wbuf[((size_t)(b * 83 + ch)) * HW_ + r];
    s += v; qq += v * v;
  }
#pragma unroll
  for (int m = 1; m < 64; m <<= 1) {
    s += __shfl_xor(s, m, 64);
    qq += __shfl_xor(qq, m, 64);
  }
  __shared__ float rs[4], rq[4];
  const int lane = threadIdx.x & 63, wv = threadIdx.x >> 6;
  if (lane == 0) { rs[wv] = s; rq[wv] = qq; }
  __syncthreads();
  if (threadIdx.x == 0) {
    float ts = rs[0] + rs[1] + rs[2] + rs[3];
    float tq = rq[0] + rq[1] + rq[2] + rq[3];
    atomicAdd(&stat[ch], ts);
    atomicAdd(&stat[80 + ch], tq);
  }
}

// ---------------------------------------------------------------------------
// K1b: finalize BN mean / invstd
// ---------------------------------------------------------------------------
__global__ void k_bn_finalize(float* __restrict__ stat)
{
  int ch = threadIdx.x;
  if (ch < 80) {
    const float n = 1.f / (float)BHW_;
    float m = stat[ch] * n;
    float var = stat[80 + ch] * n - m * m;
    stat[160 + ch] = m;
    stat[240 + ch] = rsqrtf(var + 1e-5f);
  }
}

// ---------------------------------------------------------------------------
// K2: weight generation. Strict phases: load 83 -> compute kout[83] -> write.
// ---------------------------------------------------------------------------
__global__ __launch_bounds__(256, 2) void k_weights(
    float* __restrict__ wbuf, float* __restrict__ conf,
    const float* __restrict__ prm, const float* __restrict__ stat)
{
  const int p = blockIdx.x * 256 + threadIdx.x;
  const int b = p / HW_, q = p - b * HW_;
  float* base = wbuf + ((size_t)b * 83) * HW_ + q;

  float cv[83];
#pragma unroll
  for (int ch = 0; ch < 83; ++ch) cv[ch] = base[(size_t)ch * HW_];

  const float* mean = stat + 160;
  const float* istd = stat + 240;
#pragma unroll
  for (int ch = 0; ch < 8; ++ch)
    cv[ch] = fmaxf(0.f, (cv[ch] - mean[ch]) * istd[ch] * prm[OG3 + ch] + prm[OB3 + ch]);
#pragma unroll
  for (int ch = 0; ch < 24; ++ch)
    cv[8 + ch] = fmaxf(0.f, (cv[8 + ch] - mean[8 + ch]) * istd[8 + ch] * prm[OG5 + ch] + prm[OB5 + ch]);
#pragma unroll
  for (int ch = 0; ch < 48; ++ch)
    cv[32 + ch] = fmaxf(0.f, (cv[32 + ch] - mean[32 + ch]) * istd[32 + ch] * prm[OG7 + ch] + prm[OB7 + ch]);

  float kout[83];

  // ---- pk=3: cv[0..7] -> kout[0..8] ----
  {
    float s = 0.f;
#pragma unroll
    for (int i = 0; i < 8; ++i) s += cv[i];
    float inv = 1.f / (s + 1e-6f);
    float wn[8]; float sn = 0.f;
#pragma unroll
    for (int i = 0; i < 8; ++i) { wn[i] = cv[i] * inv; sn += wn[i]; }
    float kk[9];
#pragma unroll
    for (int j = 0; j < 4; ++j) kk[j] = wn[j];
    kk[4] = 1.f - sn;
#pragma unroll
    for (int j = 0; j < 4; ++j) kk[5 + j] = wn[4 + j];
    float sg = prm[OSIG + 0];
    float a = 0.5f / (sg * sg);
    float e1 = expf(-a);
    float g1[3] = {e1, 1.f, e1};
    float tot = 0.f;
#pragma unroll
    for (int j = 0; j < 9; ++j) { kk[j] *= g1[j / 3] * g1[j % 3]; tot += kk[j]; }
    float rr = 1.f / fmaxf(tot, 1e-7f);
#pragma unroll
    for (int j = 0; j < 9; ++j) kout[j] = kk[j] * rr;
  }
  // ---- pk=5: cv[8..31] -> kout[9..33] ----
  {
    float s = 0.f;
#pragma unroll
    for (int i = 0; i < 24; ++i) s += cv[8 + i];
    float inv = 1.f / (s + 1e-6f);
    float wn[24]; float sn = 0.f;
#pragma unroll
    for (int i = 0; i < 24; ++i) { wn[i] = cv[8 + i] * inv; sn += wn[i]; }
    float kk[25];
#pragma unroll
    for (int j = 0; j < 12; ++j) kk[j] = wn[j];
    kk[12] = 1.f - sn;
#pragma unroll
    for (int j = 0; j < 12; ++j) kk[13 + j] = wn[12 + j];
    float sg = prm[OSIG + 1];
    float a = 0.5f / (sg * sg);
    float ea = expf(-a), eb = expf(-0.25f * a);
    float g1[5] = {ea, eb, 1.f, eb, ea};
    float tot = 0.f;
#pragma unroll
    for (int j = 0; j < 25; ++j) { kk[j] *= g1[j / 5] * g1[j % 5]; tot += kk[j]; }
    float rr = 1.f / fmaxf(tot, 1e-7f);
#pragma unroll
    for (int j = 0; j < 25; ++j) kout[9 + j] = kk[j] * rr;
  }
  // ---- pk=7: cv[32..79] -> kout[34..82] ----
  {
    float s = 0.f;
#pragma unroll
    for (int i = 0; i < 48; ++i) s += cv[32 + i];
    float inv = 1.f / (s + 1e-6f);
    float wn[48]; float sn = 0.f;
#pragma unroll
    for (int i = 0; i < 48; ++i) { wn[i] = cv[32 + i] * inv; sn += wn[i]; }
    float kk[49];
#pragma unroll
    for (int j = 0; j < 24; ++j) kk[j] = wn[j];
    kk[24] = 1.f - sn;
#pragma unroll
    for (int j = 0; j < 24; ++j) kk[25 + j] = wn[24 + j];
    float sg = prm[OSIG + 2];
    float a = 0.5f / (sg * sg);
    float ea = expf(-a), eb = expf(-(4.f / 9.f) * a), ec = expf(-(1.f / 9.f) * a);
    float g1[7] = {ea, eb, ec, 1.f, ec, eb, ea};
    float tot = 0.f;
#pragma unroll
    for (int j = 0; j < 49; ++j) { kk[j] *= g1[j / 7] * g1[j % 7]; tot += kk[j]; }
    float rr = 1.f / fmaxf(tot, 1e-7f);
#pragma unroll
    for (int j = 0; j < 49; ++j) kout[34 + j] = kk[j] * rr;
  }

#pragma unroll
  for (int ch = 0; ch < 83; ++ch) base[(size_t)ch * HW_] = kout[ch];

  // ---- conf softmax over ck channels ----
  {
    float c0 = cv[80] + prm[OCKB + 0];
    float c1 = cv[81] + prm[OCKB + 1];
    float c2 = cv[82] + prm[OCKB + 2];
    float m = fmaxf(c0, fmaxf(c1, c2));
    float e0 = expf(c0 - m), e1 = expf(c1 - m), e2 = expf(c2 - m);
    float inv = 1.f / (e0 + e1 + e2);
    float* cf = conf + ((size_t)b * 3) * HW_ + q;
    cf[0] = e0 * inv;
    cf[(size_t)HW_] = e1 * inv;
    cf[(size_t)2 * HW_] = e2 * inv;
  }
}

// ---------------------------------------------------------------------------
// K3: direct propagation step, all three branches. One thread per pixel.
// ---------------------------------------------------------------------------
__global__ __launch_bounds__(256, 2) void k_prop(
    const float* __restrict__ wbuf, const float* __restrict__ conf,
    const void* __restrict__ rawhn,
    const float* __restrict__ h3i, const float* __restrict__ h5i,
    const float* __restrict__ h7i,
    float* __restrict__ h3o, float* __restrict__ h5o, float* __restrict__ h7o,
    float* __restrict__ combo, int in_raw, const int* __restrict__ flags)
{
  const int isbf = flags[1];
  const int p = blockIdx.x * 256 + threadIdx.x;
  const int b = p / HW_, q = p - b * HW_;
  const int y = q / W_, x = q - y * W_;
  const size_t bo = (size_t)b * HW_;
  const float* wb = wbuf + ((size_t)b * 83) * HW_ + q;

  float a3 = 0.f, a5 = 0.f, a7 = 0.f;
#pragma unroll
  for (int j = 0; j < 9; ++j) {
    int gy = y + j / 3 - 1, gx = x + j % 3 - 1;
    float v = 0.f;
    if ((unsigned)gy < H_ && (unsigned)gx < W_) {
      size_t gi = bo + (size_t)gy * W_ + gx;
      v = in_raw ? dload(rawhn, gi, isbf) : h3i[gi];
    }
    a3 = fmaf(wb[(size_t)j * HW_], v, a3);
  }
#pragma unroll
  for (int j = 0; j < 25; ++j) {
    int gy = y + j / 5 - 2, gx = x + j % 5 - 2;
    float v = 0.f;
    if ((unsigned)gy < H_ && (unsigned)gx < W_) {
      size_t gi = bo + (size_t)gy * W_ + gx;
      v = in_raw ? dload(rawhn, gi, isbf) : h5i[gi];
    }
    a5 = fmaf(wb[(size_t)(9 + j) * HW_], v, a5);
  }
#pragma unroll
  for (int j = 0; j < 49; ++j) {
    int gy = y + j / 7 - 3, gx = x + j % 7 - 3;
    float v = 0.f;
    if ((unsigned)gy < H_ && (unsigned)gx < W_) {
      size_t gi = bo + (size_t)gy * W_ + gx;
      v = in_raw ? dload(rawhn, gi, isbf) : h7i[gi];
    }
    a7 = fmaf(wb[(size_t)(34 + j) * HW_], v, a7);
  }
  h3o[bo + q] = a3;
  h5o[bo + q] = a5;
  h7o[bo + q] = a7;
  if (combo) {
    const float* cf = conf + ((size_t)b * 3) * HW_ + q;
    combo[bo + q] = cf[0] * a3 + cf[(size_t)HW_] * a5 + cf[(size_t)2 * HW_] * a7;
  }
}

// ---------------------------------------------------------------------------
// K4: direct final conv (67ch -> 3) + softmax + dot. One thread per pixel.
// ---------------------------------------------------------------------------
__global__ __launch_bounds__(256, 2) void k_final(
    const void* __restrict__ fout, const void* __restrict__ rawhn,
    const float* __restrict__ mid, const float* __restrict__ fin,
    const float* __restrict__ prm, float* __restrict__ out,
    const int* __restrict__ flags)
{
  const int isbf_f = flags[0];
  const int isbf_h = flags[1];
  const float* ctw = prm + OCT;
  const int p = blockIdx.x * 256 + threadIdx.x;
  const int b = p / HW_, q = p - b * HW_;
  const int y = q / W_, x = q - y * W_;
  const size_t bo = (size_t)b * HW_;

  size_t toff[9]; bool tok[9];
#pragma unroll
  for (int j = 0; j < 9; ++j) {
    int gy = y + j / 3 - 1, gx = x + j % 3 - 1;
    tok[j] = (unsigned)gy < H_ && (unsigned)gx < W_;
    toff[j] = (size_t)(b * 64) * HW_ + (size_t)gy * W_ + gx;
  }

  float l0 = prm[OCTB + 0], l1 = prm[OCTB + 1], l2 = prm[OCTB + 2];

  for (int ic = 0; ic < 64; ++ic) {
#pragma unroll
    for (int j = 0; j < 9; ++j) {
      float v = tok[j] ? dload(fout, toff[j] + (size_t)ic * HW_, isbf_f) : 0.f;
      l0 = fmaf(v, ctw[(0 * 67 + ic) * 9 + j], l0);
      l1 = fmaf(v, ctw[(1 * 67 + ic) * 9 + j], l1);
      l2 = fmaf(v, ctw[(2 * 67 + ic) * 9 + j], l2);
    }
  }
#pragma unroll
  for (int c = 0; c < 3; ++c) {
    const int icg = 64 + c;
#pragma unroll
    for (int j = 0; j < 9; ++j) {
      int gy = y + j / 3 - 1, gx = x + j % 3 - 1;
      float v = 0.f;
      if ((unsigned)gy < H_ && (unsigned)gx < W_) {
        size_t gi = bo + (size_t)gy * W_ + gx;
        v = (c == 0) ? dload(rawhn, gi, isbf_h) : (c == 1) ? mid[gi] : fin[gi];
      }
      l0 = fmaf(v, ctw[(0 * 67 + icg) * 9 + j], l0);
      l1 = fmaf(v, ctw[(1 * 67 + icg) * 9 + j], l1);
      l2 = fmaf(v, ctw[(2 * 67 + icg) * 9 + j], l2);
    }
  }
  float m = fmaxf(l0, fmaxf(l1, l2));
  float e0 = expf(l0 - m), e1 = expf(l1 - m), e2 = expf(l2 - m);
  float inv = 1.f / (e0 + e1 + e2);
  float h0c = dload(rawhn, bo + q, isbf_h);
  float r = (e0 * h0c + e1 * mid[bo + q] + e2 * fin[bo + q]) * inv;
  out[bo + q] = r;
}

// ---------------------------------------------------------------------------
// Host launch
// ---------------------------------------------------------------------------
extern "C" void kernel_launch(void* const* d_in, const int* in_sizes, int n_in,
                              void* d_out, int out_size, void* d_ws, size_t ws_size,
                              hipStream_t stream)
{
  static const int EXP[19] = {20971520, 327680, 327680, 4608, 8, 8, 13824, 24, 24,
                              27648, 48, 48, 1728, 3, 1809, 3, 1, 1, 1};
  const void* P[19];
  bool match = (n_in >= 19);
  for (int i = 0; i < 19 && match; ++i) if (in_sizes[i] != EXP[i]) match = false;
  if (match) {
    for (int i = 0; i < 19; ++i) P[i] = d_in[i];
  } else {
    bool used[64] = {false};
    for (int t = 0; t < 19; ++t) {
      P[t] = d_in[t < n_in ? t : 0];
      for (int i = 0; i < n_in && i < 64; ++i)
        if (!used[i] && in_sizes[i] == EXP[t]) { P[t] = d_in[i]; used[i] = true; break; }
    }
  }
  const void* fout = P[0];
  const void* hn   = P[1];
  float* out = (float*)d_out;

  // ws layout (floats), small buffers FIRST:
  // [0,32) flags(18 ints) | [32,352) stat | [352,50138) prm | big @50176
  float* ws    = (float*)d_ws;
  int*   flags = (int*)ws;
  float* stat  = ws + 32;
  float* prm   = ws + 352;
  float* big   = ws + 50176;
  float* wbuf  = big;                              // 83*BHW
  float* conf  = wbuf + (size_t)83 * BHW_;         // 3*BHW
  float* hnA   = conf + (size_t)3 * BHW_;          // 3*BHW
  float* hnB   = hnA + (size_t)3 * BHW_;           // 3*BHW
  float* midb  = hnB + (size_t)3 * BHW_;           // BHW
  float* finb  = midb + (size_t)BHW_;              // BHW

  (void)hipMemsetAsync(stat, 0, 160 * sizeof(float), stream);

  k_detect<<<18, 512, 0, stream>>>(
      P[0], P[1], P[3], P[4], P[5], P[6], P[7], P[8],
      P[9], P[10], P[11], P[12], P[13], P[14], P[15],
      P[16], P[17], P[18], flags);

  k_cvt<<<(PRM_TOT + 255) / 256, 256, 0, stream>>>(
      P[3], P[6], P[9], P[12], P[14],
      P[4], P[5], P[7], P[8], P[10], P[11],
      P[13], P[15], P[16], P[17], P[18], prm, flags);

  k_conv_direct<<<1280, 256, 0, stream>>>(fout, prm, wbuf, flags);
  k_stats<<<dim3(32, 80), 256, 0, stream>>>(wbuf, stat);
  k_bn_finalize<<<1, 128, 0, stream>>>(stat);
  k_weights<<<1280, 256, 0, stream>>>(wbuf, conf, prm, stat);

  const float* i3 = nullptr;
  const float* i5 = nullptr;
  const float* i7 = nullptr;
  for (int it = 0; it < 6; ++it) {
    float* base = (it & 1) ? hnB : hnA;
    float* o3 = base;
    float* o5 = base + (size_t)BHW_;
    float* o7 = base + (size_t)2 * BHW_;
    float* combo = (it == 2) ? midb : (it == 5) ? finb : nullptr;
    k_prop<<<1280, 256, 0, stream>>>(
        wbuf, conf, hn, (it == 0) ? hnA : i3, (it == 0) ? hnA : i5,
        (it == 0) ? hnA : i7, o3, o5, o7, combo, (it == 0) ? 1 : 0, flags);
    i3 = o3; i5 = o5; i7 = o7;
  }

  k_final<<<1280, 256, 0, stream>>>(fout, hn, midb, finb, prm, out, flags);
}

// Round 9
// 1228.949 us; speedup vs baseline: 1.6539x; 1.0978x over previous
//
#include <hip/hip_runtime.h>
#include <hip/hip_bf16.h>
#include <math.h>

#define W_    320
#define H_    256
#define HW_   81920      // H_*W_
#define BHW_  327680     // 4*HW_
#define PRM_TOT 49786

// prm layout offsets (floats)
#define OW3  0
#define OW5  4608
#define OW7  18432
#define OCK  46080
#define OCT  47808
#define OG3  49617
#define OB3  49625
#define OG5  49633
#define OB5  49657
#define OG7  49681
#define OB7  49729
#define OCKB 49777
#define OCTB 49780
#define OSIG 49783

__device__ __forceinline__ float dload(const void* p, size_t i, int isbf) {
  return isbf ? __bfloat162float(((const __hip_bfloat16*)p)[i])
              : ((const float*)p)[i];
}

// ---------------------------------------------------------------------------
// Per-tensor dtype detector (kept for robustness; observed: all f32).
// ---------------------------------------------------------------------------
__global__ __launch_bounds__(512) void k_detect(
    const void* t0, const void* t1, const void* t2, const void* t3,
    const void* t4, const void* t5, const void* t6, const void* t7,
    const void* t8, const void* t9, const void* t10, const void* t11,
    const void* t12, const void* t13, const void* t14, const void* t15,
    const void* t16, const void* t17, int* __restrict__ flags)
{
  __shared__ int c_other, c_zeven, c_zodd, c_m;
  const void* ptrs[18] = {t0,t1,t2,t3,t4,t5,t6,t7,t8,t9,
                          t10,t11,t12,t13,t14,t15,t16,t17};
  const int ns[18] = {20971520, 327680, 4608, 8, 8, 13824, 24, 24,
                      27648, 48, 48, 1728, 3, 1809, 3, 1, 1, 1};
  const int tensor = blockIdx.x;
  const int n = ns[tensor];
  const unsigned short* u = (const unsigned short*)ptrs[tensor];
  if (threadIdx.x == 0) { c_other = 0; c_zeven = 0; c_zodd = 0; c_m = 0; }
  __syncthreads();
  {
    int k = threadIdx.x >> 1;
    long long pos = (long long)k * n / 256;
    int j = ((int)pos & ~1) + (threadIdx.x & 1);
    if (j < n) {
      unsigned short v = u[j];
      int e = (v >> 7) & 0xFF;
      atomicAdd(&c_m, 1);
      if (v != 0 && (e < 90 || e > 150)) atomicAdd(&c_other, 1);
      if (v == 0) {
        if (j & 1) atomicAdd(&c_zodd, 1); else atomicAdd(&c_zeven, 1);
      }
    }
  }
  __syncthreads();
  if (threadIdx.x == 0) {
    int isf32;
    if (n == 1) isf32 = (u[0] == 0);
    else        isf32 = (4 * c_other >= c_m) ||
                        (2 * (c_zeven - c_zodd) >= c_m);
    flags[tensor] = isf32 ? 0 : 1;
  }
}

// ---------------------------------------------------------------------------
// K0: convert params to f32 staging `prm` (per-tensor dtype).
// Note: [OW3,OCT) is already a contiguous channel-major weight bank
// wall[83][64][9] (w3|w5|w7|ck concatenated) — k_conv_g indexes it directly.
// ---------------------------------------------------------------------------
__global__ __launch_bounds__(256) void k_cvt(
    const void* w3c, const void* w5c, const void* w7c, const void* ckw, const void* ctw,
    const void* g3, const void* b3, const void* g5, const void* b5,
    const void* g7, const void* b7, const void* ckb, const void* ctb,
    const void* s3, const void* s5, const void* s7,
    float* __restrict__ prm, const int* __restrict__ flags)
{
  int j = blockIdx.x * 256 + threadIdx.x;
  if (j >= PRM_TOT) return;
  const void* src; int off; int fid;
  if      (j < OW5)    { src = w3c; off = OW3;  fid = 2; }
  else if (j < OW7)    { src = w5c; off = OW5;  fid = 5; }
  else if (j < OCK)    { src = w7c; off = OW7;  fid = 8; }
  else if (j < OCT)    { src = ckw; off = OCK;  fid = 11; }
  else if (j < OG3)    { src = ctw; off = OCT;  fid = 13; }
  else if (j < OB3)    { src = g3;  off = OG3;  fid = 3; }
  else if (j < OG5)    { src = b3;  off = OB3;  fid = 4; }
  else if (j < OB5)    { src = g5;  off = OG5;  fid = 6; }
  else if (j < OG7)    { src = b5;  off = OB5;  fid = 7; }
  else if (j < OB7)    { src = g7;  off = OG7;  fid = 9; }
  else if (j < OCKB)   { src = b7;  off = OB7;  fid = 10; }
  else if (j < OCTB)   { src = ckb; off = OCKB; fid = 12; }
  else if (j < OSIG)   { src = ctb; off = OCTB; fid = 14; }
  else if (j < OSIG+1) { src = s3;  off = OSIG;   fid = 15; }
  else if (j < OSIG+2) { src = s5;  off = OSIG+1; fid = 16; }
  else                 { src = s7;  off = OSIG+2; fid = 17; }
  prm[j] = dload(src, j - off, flags[fid]);
}

// ---------------------------------------------------------------------------
// K1: 3x3 conv 64->83, channel-grouped. grid=(1280, 6): block = 256 pixels
// x 16 output channels. Accumulators are 16 NAMED SCALARS (R8 lesson:
// LLVM refuses to promote large allocas — acc[83] lived in scratch even
// with static indices; 77% of k_conv time was scratch RMW stall).
// Weight pointers are wave-uniform (SGPR, scalar loads).
// ---------------------------------------------------------------------------
__global__ __launch_bounds__(256) void k_conv_g(
    const void* __restrict__ fout, const float* __restrict__ prm,
    float* __restrict__ wbuf, const int* __restrict__ flags)
{
  const int isbf = flags[0];
  const int p = blockIdx.x * 256 + threadIdx.x;   // 1280*256 == BHW
  const int g16 = blockIdx.y * 16;                // first channel of group
  const int b = p / HW_, q = p - b * HW_;
  const int y = q / W_, x = q - y * W_;

  int toff[9]; bool tok[9];
#pragma unroll
  for (int j = 0; j < 9; ++j) {
    int gy = y + j / 3 - 1, gx = x + j % 3 - 1;
    tok[j] = (unsigned)gy < H_ && (unsigned)gx < W_;
    toff[j] = gy * W_ + gx;
  }
  const size_t fbase = (size_t)b * 64 * HW_;

  // Wave-uniform per-channel weight bases (clamped for the 3-wide tail group;
  // clamped lanes compute garbage that is masked at store).
#define CHP(I) const float* wch##I = prm + (size_t)((g16 + I < 83) ? g16 + I : 82) * 576;
  CHP(0) CHP(1) CHP(2) CHP(3) CHP(4) CHP(5) CHP(6) CHP(7)
  CHP(8) CHP(9) CHP(10) CHP(11) CHP(12) CHP(13) CHP(14) CHP(15)
#undef CHP

  float a00=0.f,a01=0.f,a02=0.f,a03=0.f,a04=0.f,a05=0.f,a06=0.f,a07=0.f;
  float a08=0.f,a09=0.f,a10=0.f,a11=0.f,a12=0.f,a13=0.f,a14=0.f,a15=0.f;

  for (int ic = 0; ic < 64; ++ic) {
    float t[9];
#pragma unroll
    for (int j = 0; j < 9; ++j)
      t[j] = tok[j] ? dload(fout, fbase + (size_t)ic * HW_ + toff[j], isbf) : 0.f;
    const int wo = ic * 9;
#define ACC1(A, I) { const float* wb = wch##I + wo; \
    A = fmaf(t[0],wb[0],A); A = fmaf(t[1],wb[1],A); A = fmaf(t[2],wb[2],A); \
    A = fmaf(t[3],wb[3],A); A = fmaf(t[4],wb[4],A); A = fmaf(t[5],wb[5],A); \
    A = fmaf(t[6],wb[6],A); A = fmaf(t[7],wb[7],A); A = fmaf(t[8],wb[8],A); }
    ACC1(a00,0) ACC1(a01,1) ACC1(a02,2) ACC1(a03,3)
    ACC1(a04,4) ACC1(a05,5) ACC1(a06,6) ACC1(a07,7)
    ACC1(a08,8) ACC1(a09,9) ACC1(a10,10) ACC1(a11,11)
    ACC1(a12,12) ACC1(a13,13) ACC1(a14,14) ACC1(a15,15)
#undef ACC1
  }

#define ST1(A, I) if (g16 + I < 83) \
    wbuf[((size_t)b * 83 + g16 + I) * HW_ + q] = A;
  ST1(a00,0) ST1(a01,1) ST1(a02,2) ST1(a03,3)
  ST1(a04,4) ST1(a05,5) ST1(a06,6) ST1(a07,7)
  ST1(a08,8) ST1(a09,9) ST1(a10,10) ST1(a11,11)
  ST1(a12,12) ST1(a13,13) ST1(a14,14) ST1(a15,15)
#undef ST1
}

// ---------------------------------------------------------------------------
// K1s: BN statistics over wbuf channels 0..79.
// ---------------------------------------------------------------------------
__global__ __launch_bounds__(256) void k_stats(
    const float* __restrict__ wbuf, float* __restrict__ stat)
{
  const int ch = blockIdx.y;
  float s = 0.f, qq = 0.f;
  for (int idx = blockIdx.x * 256 + threadIdx.x; idx < BHW_;
       idx += gridDim.x * 256) {
    int b = idx / HW_, r = idx - b * HW_;
    float v = wbuf[((size_t)(b * 83 + ch)) * HW_ + r];
    s += v; qq += v * v;
  }
#pragma unroll
  for (int m = 1; m < 64; m <<= 1) {
    s += __shfl_xor(s, m, 64);
    qq += __shfl_xor(qq, m, 64);
  }
  __shared__ float rs[4], rq[4];
  const int lane = threadIdx.x & 63, wv = threadIdx.x >> 6;
  if (lane == 0) { rs[wv] = s; rq[wv] = qq; }
  __syncthreads();
  if (threadIdx.x == 0) {
    float ts = rs[0] + rs[1] + rs[2] + rs[3];
    float tq = rq[0] + rq[1] + rq[2] + rq[3];
    atomicAdd(&stat[ch], ts);
    atomicAdd(&stat[80 + ch], tq);
  }
}

// ---------------------------------------------------------------------------
// K1b: finalize BN mean / invstd
// ---------------------------------------------------------------------------
__global__ void k_bn_finalize(float* __restrict__ stat)
{
  int ch = threadIdx.x;
  if (ch < 80) {
    const float n = 1.f / (float)BHW_;
    float m = stat[ch] * n;
    float var = stat[80 + ch] * n - m * m;
    stat[160 + ch] = m;
    stat[240 + ch] = rsqrtf(var + 1e-5f);
  }
}

// ---------------------------------------------------------------------------
// K2: weight generation. (Known: large local arrays live in scratch; cost
// is modest vs k_conv — next optimization target after this round's data.)
// ---------------------------------------------------------------------------
__global__ __launch_bounds__(256, 2) void k_weights(
    float* __restrict__ wbuf, float* __restrict__ conf,
    const float* __restrict__ prm, const float* __restrict__ stat)
{
  const int p = blockIdx.x * 256 + threadIdx.x;
  const int b = p / HW_, q = p - b * HW_;
  float* base = wbuf + ((size_t)b * 83) * HW_ + q;

  float cv[83];
#pragma unroll
  for (int ch = 0; ch < 83; ++ch) cv[ch] = base[(size_t)ch * HW_];

  const float* mean = stat + 160;
  const float* istd = stat + 240;
#pragma unroll
  for (int ch = 0; ch < 8; ++ch)
    cv[ch] = fmaxf(0.f, (cv[ch] - mean[ch]) * istd[ch] * prm[OG3 + ch] + prm[OB3 + ch]);
#pragma unroll
  for (int ch = 0; ch < 24; ++ch)
    cv[8 + ch] = fmaxf(0.f, (cv[8 + ch] - mean[8 + ch]) * istd[8 + ch] * prm[OG5 + ch] + prm[OB5 + ch]);
#pragma unroll
  for (int ch = 0; ch < 48; ++ch)
    cv[32 + ch] = fmaxf(0.f, (cv[32 + ch] - mean[32 + ch]) * istd[32 + ch] * prm[OG7 + ch] + prm[OB7 + ch]);

  float kout[83];

  // ---- pk=3: cv[0..7] -> kout[0..8] ----
  {
    float s = 0.f;
#pragma unroll
    for (int i = 0; i < 8; ++i) s += cv[i];
    float inv = 1.f / (s + 1e-6f);
    float wn[8]; float sn = 0.f;
#pragma unroll
    for (int i = 0; i < 8; ++i) { wn[i] = cv[i] * inv; sn += wn[i]; }
    float kk[9];
#pragma unroll
    for (int j = 0; j < 4; ++j) kk[j] = wn[j];
    kk[4] = 1.f - sn;
#pragma unroll
    for (int j = 0; j < 4; ++j) kk[5 + j] = wn[4 + j];
    float sg = prm[OSIG + 0];
    float a = 0.5f / (sg * sg);
    float e1 = expf(-a);
    float g1[3] = {e1, 1.f, e1};
    float tot = 0.f;
#pragma unroll
    for (int j = 0; j < 9; ++j) { kk[j] *= g1[j / 3] * g1[j % 3]; tot += kk[j]; }
    float rr = 1.f / fmaxf(tot, 1e-7f);
#pragma unroll
    for (int j = 0; j < 9; ++j) kout[j] = kk[j] * rr;
  }
  // ---- pk=5: cv[8..31] -> kout[9..33] ----
  {
    float s = 0.f;
#pragma unroll
    for (int i = 0; i < 24; ++i) s += cv[8 + i];
    float inv = 1.f / (s + 1e-6f);
    float wn[24]; float sn = 0.f;
#pragma unroll
    for (int i = 0; i < 24; ++i) { wn[i] = cv[8 + i] * inv; sn += wn[i]; }
    float kk[25];
#pragma unroll
    for (int j = 0; j < 12; ++j) kk[j] = wn[j];
    kk[12] = 1.f - sn;
#pragma unroll
    for (int j = 0; j < 12; ++j) kk[13 + j] = wn[12 + j];
    float sg = prm[OSIG + 1];
    float a = 0.5f / (sg * sg);
    float ea = expf(-a), eb = expf(-0.25f * a);
    float g1[5] = {ea, eb, 1.f, eb, ea};
    float tot = 0.f;
#pragma unroll
    for (int j = 0; j < 25; ++j) { kk[j] *= g1[j / 5] * g1[j % 5]; tot += kk[j]; }
    float rr = 1.f / fmaxf(tot, 1e-7f);
#pragma unroll
    for (int j = 0; j < 25; ++j) kout[9 + j] = kk[j] * rr;
  }
  // ---- pk=7: cv[32..79] -> kout[34..82] ----
  {
    float s = 0.f;
#pragma unroll
    for (int i = 0; i < 48; ++i) s += cv[32 + i];
    float inv = 1.f / (s + 1e-6f);
    float wn[48]; float sn = 0.f;
#pragma unroll
    for (int i = 0; i < 48; ++i) { wn[i] = cv[32 + i] * inv; sn += wn[i]; }
    float kk[49];
#pragma unroll
    for (int j = 0; j < 24; ++j) kk[j] = wn[j];
    kk[24] = 1.f - sn;
#pragma unroll
    for (int j = 0; j < 24; ++j) kk[25 + j] = wn[24 + j];
    float sg = prm[OSIG + 2];
    float a = 0.5f / (sg * sg);
    float ea = expf(-a), eb = expf(-(4.f / 9.f) * a), ec = expf(-(1.f / 9.f) * a);
    float g1[7] = {ea, eb, ec, 1.f, ec, eb, ea};
    float tot = 0.f;
#pragma unroll
    for (int j = 0; j < 49; ++j) { kk[j] *= g1[j / 7] * g1[j % 7]; tot += kk[j]; }
    float rr = 1.f / fmaxf(tot, 1e-7f);
#pragma unroll
    for (int j = 0; j < 49; ++j) kout[34 + j] = kk[j] * rr;
  }

#pragma unroll
  for (int ch = 0; ch < 83; ++ch) base[(size_t)ch * HW_] = kout[ch];

  // ---- conf softmax over ck channels ----
  {
    float c0 = cv[80] + prm[OCKB + 0];
    float c1 = cv[81] + prm[OCKB + 1];
    float c2 = cv[82] + prm[OCKB + 2];
    float m = fmaxf(c0, fmaxf(c1, c2));
    float e0 = expf(c0 - m), e1 = expf(c1 - m), e2 = expf(c2 - m);
    float inv = 1.f / (e0 + e1 + e2);
    float* cf = conf + ((size_t)b * 3) * HW_ + q;
    cf[0] = e0 * inv;
    cf[(size_t)HW_] = e1 * inv;
    cf[(size_t)2 * HW_] = e2 * inv;
  }
}

// ---------------------------------------------------------------------------
// K3: direct propagation step, all three branches. One thread per pixel.
// ---------------------------------------------------------------------------
__global__ __launch_bounds__(256, 2) void k_prop(
    const float* __restrict__ wbuf, const float* __restrict__ conf,
    const void* __restrict__ rawhn,
    const float* __restrict__ h3i, const float* __restrict__ h5i,
    const float* __restrict__ h7i,
    float* __restrict__ h3o, float* __restrict__ h5o, float* __restrict__ h7o,
    float* __restrict__ combo, int in_raw, const int* __restrict__ flags)
{
  const int isbf = flags[1];
  const int p = blockIdx.x * 256 + threadIdx.x;
  const int b = p / HW_, q = p - b * HW_;
  const int y = q / W_, x = q - y * W_;
  const size_t bo = (size_t)b * HW_;
  const float* wb = wbuf + ((size_t)b * 83) * HW_ + q;

  float a3 = 0.f, a5 = 0.f, a7 = 0.f;
#pragma unroll
  for (int j = 0; j < 9; ++j) {
    int gy = y + j / 3 - 1, gx = x + j % 3 - 1;
    float v = 0.f;
    if ((unsigned)gy < H_ && (unsigned)gx < W_) {
      size_t gi = bo + (size_t)gy * W_ + gx;
      v = in_raw ? dload(rawhn, gi, isbf) : h3i[gi];
    }
    a3 = fmaf(wb[(size_t)j * HW_], v, a3);
  }
#pragma unroll
  for (int j = 0; j < 25; ++j) {
    int gy = y + j / 5 - 2, gx = x + j % 5 - 2;
    float v = 0.f;
    if ((unsigned)gy < H_ && (unsigned)gx < W_) {
      size_t gi = bo + (size_t)gy * W_ + gx;
      v = in_raw ? dload(rawhn, gi, isbf) : h5i[gi];
    }
    a5 = fmaf(wb[(size_t)(9 + j) * HW_], v, a5);
  }
#pragma unroll
  for (int j = 0; j < 49; ++j) {
    int gy = y + j / 7 - 3, gx = x + j % 7 - 3;
    float v = 0.f;
    if ((unsigned)gy < H_ && (unsigned)gx < W_) {
      size_t gi = bo + (size_t)gy * W_ + gx;
      v = in_raw ? dload(rawhn, gi, isbf) : h7i[gi];
    }
    a7 = fmaf(wb[(size_t)(34 + j) * HW_], v, a7);
  }
  h3o[bo + q] = a3;
  h5o[bo + q] = a5;
  h7o[bo + q] = a7;
  if (combo) {
    const float* cf = conf + ((size_t)b * 3) * HW_ + q;
    combo[bo + q] = cf[0] * a3 + cf[(size_t)HW_] * a5 + cf[(size_t)2 * HW_] * a7;
  }
}

// ---------------------------------------------------------------------------
// K4: direct final conv (67ch -> 3) + softmax + dot. One thread per pixel.
// ---------------------------------------------------------------------------
__global__ __launch_bounds__(256, 2) void k_final(
    const void* __restrict__ fout, const void* __restrict__ rawhn,
    const float* __restrict__ mid, const float* __restrict__ fin,
    const float* __restrict__ prm, float* __restrict__ out,
    const int* __restrict__ flags)
{
  const int isbf_f = flags[0];
  const int isbf_h = flags[1];
  const float* ctw = prm + OCT;
  const int p = blockIdx.x * 256 + threadIdx.x;
  const int b = p / HW_, q = p - b * HW_;
  const int y = q / W_, x = q - y * W_;
  const size_t bo = (size_t)b * HW_;

  int toff[9]; bool tok[9];
#pragma unroll
  for (int j = 0; j < 9; ++j) {
    int gy = y + j / 3 - 1, gx = x + j % 3 - 1;
    tok[j] = (unsigned)gy < H_ && (unsigned)gx < W_;
    toff[j] = gy * W_ + gx;
  }
  const size_t fbase = (size_t)b * 64 * HW_;

  float l0 = prm[OCTB + 0], l1 = prm[OCTB + 1], l2 = prm[OCTB + 2];

  for (int ic = 0; ic < 64; ++ic) {
#pragma unroll
    for (int j = 0; j < 9; ++j) {
      float v = tok[j] ? dload(fout, fbase + (size_t)ic * HW_ + toff[j], isbf_f) : 0.f;
      l0 = fmaf(v, ctw[(0 * 67 + ic) * 9 + j], l0);
      l1 = fmaf(v, ctw[(1 * 67 + ic) * 9 + j], l1);
      l2 = fmaf(v, ctw[(2 * 67 + ic) * 9 + j], l2);
    }
  }
#pragma unroll
  for (int c = 0; c < 3; ++c) {
    const int icg = 64 + c;
#pragma unroll
    for (int j = 0; j < 9; ++j) {
      int gy = y + j / 3 - 1, gx = x + j % 3 - 1;
      float v = 0.f;
      if ((unsigned)gy < H_ && (unsigned)gx < W_) {
        size_t gi = bo + (size_t)gy * W_ + gx;
        v = (c == 0) ? dload(rawhn, gi, isbf_h) : (c == 1) ? mid[gi] : fin[gi];
      }
      l0 = fmaf(v, ctw[(0 * 67 + icg) * 9 + j], l0);
      l1 = fmaf(v, ctw[(1 * 67 + icg) * 9 + j], l1);
      l2 = fmaf(v, ctw[(2 * 67 + icg) * 9 + j], l2);
    }
  }
  float m = fmaxf(l0, fmaxf(l1, l2));
  float e0 = expf(l0 - m), e1 = expf(l1 - m), e2 = expf(l2 - m);
  float inv = 1.f / (e0 + e1 + e2);
  float h0c = dload(rawhn, bo + q, isbf_h);
  float r = (e0 * h0c + e1 * mid[bo + q] + e2 * fin[bo + q]) * inv;
  out[bo + q] = r;
}

// ---------------------------------------------------------------------------
// Host launch
// ---------------------------------------------------------------------------
extern "C" void kernel_launch(void* const* d_in, const int* in_sizes, int n_in,
                              void* d_out, int out_size, void* d_ws, size_t ws_size,
                              hipStream_t stream)
{
  static const int EXP[19] = {20971520, 327680, 327680, 4608, 8, 8, 13824, 24, 24,
                              27648, 48, 48, 1728, 3, 1809, 3, 1, 1, 1};
  const void* P[19];
  bool match = (n_in >= 19);
  for (int i = 0; i < 19 && match; ++i) if (in_sizes[i] != EXP[i]) match = false;
  if (match) {
    for (int i = 0; i < 19; ++i) P[i] = d_in[i];
  } else {
    bool used[64] = {false};
    for (int t = 0; t < 19; ++t) {
      P[t] = d_in[t < n_in ? t : 0];
      for (int i = 0; i < n_in && i < 64; ++i)
        if (!used[i] && in_sizes[i] == EXP[t]) { P[t] = d_in[i]; used[i] = true; break; }
    }
  }
  const void* fout = P[0];
  const void* hn   = P[1];
  float* out = (float*)d_out;

  // ws layout (floats), small buffers FIRST:
  // [0,32) flags(18 ints) | [32,352) stat | [352,50138) prm | big @50176
  float* ws    = (float*)d_ws;
  int*   flags = (int*)ws;
  float* stat  = ws + 32;
  float* prm   = ws + 352;
  float* big   = ws + 50176;
  float* wbuf  = big;                              // 83*BHW
  float* conf  = wbuf + (size_t)83 * BHW_;         // 3*BHW
  float* hnA   = conf + (size_t)3 * BHW_;          // 3*BHW
  float* hnB   = hnA + (size_t)3 * BHW_;           // 3*BHW
  float* midb  = hnB + (size_t)3 * BHW_;           // BHW
  float* finb  = midb + (size_t)BHW_;              // BHW

  (void)hipMemsetAsync(stat, 0, 160 * sizeof(float), stream);

  k_detect<<<18, 512, 0, stream>>>(
      P[0], P[1], P[3], P[4], P[5], P[6], P[7], P[8],
      P[9], P[10], P[11], P[12], P[13], P[14], P[15],
      P[16], P[17], P[18], flags);

  k_cvt<<<(PRM_TOT + 255) / 256, 256, 0, stream>>>(
      P[3], P[6], P[9], P[12], P[14],
      P[4], P[5], P[7], P[8], P[10], P[11],
      P[13], P[15], P[16], P[17], P[18], prm, flags);

  k_conv_g<<<dim3(1280, 6), 256, 0, stream>>>(fout, prm, wbuf, flags);
  k_stats<<<dim3(32, 80), 256, 0, stream>>>(wbuf, stat);
  k_bn_finalize<<<1, 128, 0, stream>>>(stat);
  k_weights<<<1280, 256, 0, stream>>>(wbuf, conf, prm, stat);

  const float* i3 = nullptr;
  const float* i5 = nullptr;
  const float* i7 = nullptr;
  for (int it = 0; it < 6; ++it) {
    float* base = (it & 1) ? hnB : hnA;
    float* o3 = base;
    float* o5 = base + (size_t)BHW_;
    float* o7 = base + (size_t)2 * BHW_;
    float* combo = (it == 2) ? midb : (it == 5) ? finb : nullptr;
    k_prop<<<1280, 256, 0, stream>>>(
        wbuf, conf, hn, (it == 0) ? hnA : i3, (it == 0) ? hnA : i5,
        (it == 0) ? hnA : i7, o3, o5, o7, combo, (it == 0) ? 1 : 0, flags);
    i3 = o3; i5 = o5; i7 = o7;
  }

  k_final<<<1280, 256, 0, stream>>>(fout, hn, midb, finb, prm, out, flags);
}